// Round 9
// baseline (88.070 us; speedup 1.0000x reference)
//
#include <hip/hip_runtime.h>
#include <climits>
#include <cstdint>

namespace {
constexpr int B = 4, N = 20000, C = 21, P = 100, NC = 20; // NC = C-1
constexpr float THR  = 0.7f;
constexpr float BIGF = 1.0e9f;
constexpr float MAXR = 4.135166556742356f; // |log(16/1000)| rounded to f32
constexpr float TAU  = 0.8f;               // prune threshold (verified post-hoc)
constexpr int NMT  = 512;                  // k_nms block size
constexpr int PCAP = NMT;                  // pruned-list capacity = 1 slot/thread
constexpr int TKN  = 2048;                 // padded topk candidate count
constexpr int TKT  = 512;                  // k_topk block size (8 waves)
constexpr int NB   = (N + 255) / 256;      // 79 k_valid blocks per image
constexpr int GPB  = 2;                    // k_valid blocks per compact block
constexpr int GB   = (NB + GPB - 1) / GPB; // 40 compact blocks per image

// ws layout (bytes)
constexpr size_t OFF_CPACK = 0;                                  // B*N*8 f32 packed cand
constexpr size_t OFF_MASK  = OFF_CPACK + (size_t)B * N * 32;     // B*N u32
constexpr size_t OFF_BCNT  = OFF_MASK  + (size_t)B * N * 4;      // B*NB i32 (+pad)
constexpr size_t OFF_VCNT  = OFF_BCNT  + 2048;                   // B i32 (+pad)
constexpr size_t OFF_OIDX  = OFF_VCNT  + 64;                     // B*NC*P i32
constexpr size_t OFF_OVAL  = OFF_OIDX  + (size_t)B * NC * P * 4; // B*NC*P i32
constexpr size_t OFF_OSC   = OFF_OVAL  + (size_t)B * NC * P * 4; // B*NC*P f32 (orig le)
constexpr size_t OFF_OBOX  = OFF_OSC   + (size_t)B * NC * P * 4; // B*NC*P f32x4
constexpr size_t OFF_SFALL = OFF_OBOX  + (size_t)B * NC * P * 16;// B*NC*N f32 fallback
} // namespace

// ---------------------------------------------------------------------------
// DPP wave64 fmax reduce (VALU-only); result broadcast via readlane 63.
// ---------------------------------------------------------------------------
template <int CTRL, int RM>
__device__ __forceinline__ float dpp_fmax(float x) {
  int t = __builtin_amdgcn_update_dpp(__float_as_int(x), __float_as_int(x),
                                      CTRL, RM, 0xF, false);
  return fmaxf(x, __int_as_float(t));
}
__device__ __forceinline__ float wave_fmax64(float x) {
  x = dpp_fmax<0x111, 0xF>(x); // row_shr:1
  x = dpp_fmax<0x112, 0xF>(x); // row_shr:2
  x = dpp_fmax<0x114, 0xF>(x); // row_shr:4
  x = dpp_fmax<0x118, 0xF>(x); // row_shr:8
  x = dpp_fmax<0x142, 0xA>(x); // row_bcast:15 -> rows 1,3
  x = dpp_fmax<0x143, 0xC>(x); // row_bcast:31 -> rows 2,3
  return __int_as_float(__builtin_amdgcn_readlane(__float_as_int(x), 63));
}
// fast native ops for the decay weights (selection-only values; exp2(-0)=1
// exactly so non-overlapping candidates stay bit-identical to np)
__device__ __forceinline__ float fast_rcp(float x) {
  return __builtin_amdgcn_rcpf(x);
}
__device__ __forceinline__ float fast_exp2(float x) {
  return __builtin_amdgcn_exp2f(x);
}
// monotonic float<->uint order map (no NaNs present)
__device__ __forceinline__ unsigned fmap(float v) {
  unsigned u = __float_as_uint(v);
  return (u & 0x80000000u) ? ~u : (u | 0x80000000u);
}
__device__ __forceinline__ float funmap(unsigned u) {
  return __uint_as_float((u & 0x80000000u) ? (u ^ 0x80000000u) : ~u);
}

// ---------------------------------------------------------------------------
// Kernel 1: per-anchor le/argmax/valid + tau bitmask + per-block valid count.
// ---------------------------------------------------------------------------
__global__ __launch_bounds__(256) void k_valid(
    const float* __restrict__ score, const float* __restrict__ logits,
    unsigned* __restrict__ mask, int* __restrict__ bcnt) {
  __shared__ int ws[4];
  int tid = threadIdx.x;
  int n = blockIdx.x * 256 + tid;
  int b = blockIdx.y;
  unsigned mk = 0;
  if (n < N) {
    int bn = b * N + n;
    float sc = score[bn];
    const float* lg = logits + (size_t)bn * C;
    float le[C];
    float ms = -INFINITY;
    int lab = 0;
    #pragma unroll
    for (int c = 0; c < C; ++c) {
      le[c] = __fmul_rn(sc, lg[c]);
      if (le[c] > ms) { ms = le[c]; lab = c; }  // strict > keeps first max
    }
    if (ms >= THR && lab > 0) {
      mk = 1u << 20;
      #pragma unroll
      for (int c = 1; c < C; ++c)
        if (le[c] >= TAU) mk |= 1u << (c - 1);
    }
    mask[bn] = mk;
  }
  unsigned long long vb = __ballot(mk != 0);
  if ((tid & 63) == 0) ws[tid >> 6] = __popcll(vb);
  __syncthreads();
  if (tid == 0) bcnt[b * NB + blockIdx.x] = ws[0] + ws[1] + ws[2] + ws[3];
}

// ---------------------------------------------------------------------------
// Kernel 2: segmented stable compaction + box decode into packed 32B records
// {x1,y1,x2,y2, n(bits), score, area, mask(bits)}. Grid (GB, B), 256 thr.
// ---------------------------------------------------------------------------
__global__ __launch_bounds__(256) void k_compact(
    const float* __restrict__ score, const float* __restrict__ regress,
    const float* __restrict__ anchors, const unsigned* __restrict__ mask,
    const int* __restrict__ bcnt, float* __restrict__ cpack,
    int* __restrict__ vcnt) {
  __shared__ int s_base[4], s_tot[4], s_scan[4];
  int g = blockIdx.x, b = blockIdx.y;
  int tid = threadIdx.x, lane = tid & 63, wid = tid >> 6;
  int idx0 = g * GPB;
  int bv = (tid < idx0) ? bcnt[b * NB + tid] : 0;
  int tv = (tid < NB) ? bcnt[b * NB + tid] : 0;
  #pragma unroll
  for (int off = 32; off; off >>= 1) {
    bv += __shfl_down(bv, off);
    tv += __shfl_down(tv, off);
  }
  if (lane == 0) { s_base[wid] = bv; s_tot[wid] = tv; }
  __syncthreads();
  int base = s_base[0] + s_base[1] + s_base[2] + s_base[3];
  if (g == 0 && tid == 0) vcnt[b] = s_tot[0] + s_tot[1] + s_tot[2] + s_tot[3];

  int n0 = g * (GPB * 256) + tid * GPB;
  unsigned bits = 0; int cnt = 0;
  #pragma unroll
  for (int j = 0; j < GPB; ++j) {
    int n = n0 + j;
    if (n < N && (mask[b * N + n] & (1u << 20))) { bits |= 1u << j; cnt++; }
  }
  int inc = cnt;
  #pragma unroll
  for (int off = 1; off < 64; off <<= 1) {
    int o = __shfl_up(inc, off);
    if (lane >= off) inc += o;
  }
  if (lane == 63) s_scan[wid] = inc;
  __syncthreads();
  int woff = 0;
  for (int k = 0; k < wid; ++k) woff += s_scan[k];
  int pos = base + woff + inc - cnt;
  #pragma unroll
  for (int j = 0; j < GPB; ++j) {
    if (!((bits >> j) & 1u)) continue;
    int n = n0 + j;
    int bn = b * N + n;
    const float* an = anchors + (size_t)n * 4;
    float ax1 = an[0], ay1 = an[1], ax2 = an[2], ay2 = an[3];
    float aw = __fsub_rn(ax2, ax1), ah = __fsub_rn(ay2, ay1);
    float acx = __fadd_rn(ax1, __fmul_rn(0.5f, aw));
    float acy = __fadd_rn(ay1, __fmul_rn(0.5f, ah));
    const float* rg = regress + (size_t)bn * 4;
    float dx = rg[0], dy = rg[1];
    float dw = fminf(fmaxf(rg[2], -MAXR), MAXR);
    float dh = fminf(fmaxf(rg[3], -MAXR), MAXR);
    float cx = __fadd_rn(acx, __fmul_rn(dx, aw));
    float cy = __fadd_rn(acy, __fmul_rn(dy, ah));
    float w = __fmul_rn(aw, expf(dw));
    float h = __fmul_rn(ah, expf(dh));
    float hw = __fmul_rn(0.5f, w), hh = __fmul_rn(0.5f, h);
    float x1 = fminf(fmaxf(__fsub_rn(cx, hw), 0.f), 1.f);
    float y1 = fminf(fmaxf(__fsub_rn(cy, hh), 0.f), 1.f);
    float x2 = fminf(fmaxf(__fadd_rn(cx, hw), 0.f), 1.f);
    float y2 = fminf(fmaxf(__fadd_rn(cy, hh), 0.f), 1.f);
    float area = __fmul_rn(__fsub_rn(x2, x1), __fsub_rn(y2, y1));
    unsigned mk = mask[bn];
    float4* cp = reinterpret_cast<float4*>(cpack) + ((size_t)b * N + pos) * 2;
    cp[0] = make_float4(x1, y1, x2, y2);
    cp[1] = make_float4(__int_as_float(n), score[bn], area, __uint_as_float(mk));
    pos++;
  }
}

// ---------------------------------------------------------------------------
// Kernel 3: soft-NMS. One block per (image,class), 512 threads, 1 slot/thread
// (the measured-best structure). Per step: decay own slot -> wave argmax
// (DPP fmax + ballot) -> lane0 publishes ONE step-tagged packed key via LDS
// atomicMax into a parity-double-buffered u64:
//   key = ((t+1)<<41) | (fmap(val)<<9) | (511-tid)
// The monotone step tag makes stale same-parity residue (step t-2) always
// lose, so no reset write is needed and one barrier/step suffices; same-tag
// comparison is (value desc, smallest slot) — bit-identical to the old
// 8-key tournament. Post-barrier: ONE ds_read_b64 gives the global winner
// (replaces 4x ds_read_b128 + 7 u64 compare-selects), then the winner box
// via uniform LDS broadcast. Decay math is the exact verified sequence
// (fast rcp/exp2; inter==0 -> wgt==1 exactly). Exhaustion keeps the final
// key value < TAU -> exact full-V fallback. s_box zero-init keeps empty
// slots NaN-free.
// ---------------------------------------------------------------------------
__global__ __launch_bounds__(NMT) void k_nms(
    const float* __restrict__ logits, const float* __restrict__ cpack,
    const int* __restrict__ vcnt, float* __restrict__ sfall,
    int* __restrict__ oidx, int* __restrict__ oval,
    float* __restrict__ osc, float* __restrict__ obox) {
  constexpr int NW = NMT / 64;
  __shared__ float4 s_box[PCAP];
  __shared__ float  s_ar[PCAP], s_s[PCAP];
  __shared__ int    s_n[PCAP];
  __shared__ int    s_selj[P];
  __shared__ int    s_wcnt[NW];
  __shared__ int    s_fail;
  __shared__ unsigned long long s_gk[2]; // parity-double-buffered global key
  __shared__ float  s_red[NW];
  __shared__ int    s_redi[NW];

  int blk = blockIdx.x;  // 0..B*NC-1
  int b = blk / NC;
  int cls = blk % NC + 1;
  int V = vcnt[b];
  int tid = threadIdx.x;
  int lane = tid & 63, wid = tid >> 6;
  const float* cpf = cpack + (size_t)b * N * 8;
  int* oi = oidx + (size_t)blk * P;
  int* ov = oval + (size_t)blk * P;
  float* os = osc + (size_t)blk * P;
  float4* ob = reinterpret_cast<float4*>(obox) + (size_t)blk * P;
  unsigned clsbit = 1u << (cls - 1);

  // zero-init s_box so empty slots read a harmless zero box
  s_box[tid] = make_float4(0.f, 0.f, 0.f, 0.f);
  if (tid == 0) { s_gk[0] = 0ull; s_gk[1] = 0ull; }

  // ---- pass 1: count candidates with le >= TAU for this class ----
  int ch = (V + NMT - 1) / NMT;
  int v0 = tid * ch, v1 = min(v0 + ch, V);
  int cnt = 0;
  for (int v = v0; v < v1; ++v) {
    unsigned mk = __float_as_uint(cpf[(size_t)v * 8 + 7]);
    if (mk & clsbit) cnt++;
  }
  int inc = cnt;
  #pragma unroll
  for (int off = 1; off < 64; off <<= 1) {
    int o = __shfl_up(inc, off);
    if (lane >= off) inc += o;
  }
  if (lane == 63) s_wcnt[wid] = inc;
  __syncthreads();
  int woff = 0;
  for (int k = 0; k < wid; ++k) woff += s_wcnt[k];
  int pcnt = 0;
  #pragma unroll
  for (int k = 0; k < NW; ++k) pcnt += s_wcnt[k];
  int pos = woff + inc - cnt;
  // ---- pass 2: fill LDS for passing candidates (stable order) ----
  for (int v = v0; v < v1; ++v) {
    const float4* cp = reinterpret_cast<const float4*>(cpf) + (size_t)v * 2;
    float4 f2 = cp[1];
    unsigned mk = __float_as_uint(f2.w);
    if (mk & clsbit) {
      if (pos < PCAP) {
        float4 f1 = cp[0];
        int n = __float_as_int(f2.x);
        float lg = logits[(size_t)(b * N + n) * C + cls];
        s_s[pos]   = __fmul_rn(f2.y, lg);
        s_box[pos] = f1;
        s_ar[pos]  = f2.z;
        s_n[pos]   = n;
      }
      pos++;
    }
  }
  __syncthreads();

  bool fail0 = (pcnt > PCAP);
  if (!fail0) {
    // ---- per-thread single-slot state ----
    bool in = tid < pcnt;
    float4 q = s_box[tid];
    float sr = in ? s_s[tid] : -INFINITY;
    float qx = q.x, qy = q.y, qz = q.z, qw = q.w;
    float pa = in ? s_ar[tid] : 0.f;
    unsigned long long kb = 0ull;

    for (int t = 0; t < P; ++t) {
      int par = t & 1;
      // wave argmax of sr (ties -> smallest lane = smallest slot)
      float lm = wave_fmax64(sr);
      unsigned long long bm = __ballot(sr == lm);
      int lane_w = __ffsll(bm) - 1;
      if (lane == 0) {
        unsigned inv = 511u - (unsigned)(wid * 64 + lane_w);
        unsigned long long key = ((unsigned long long)(t + 1) << 41) |
                                 ((unsigned long long)fmap(lm) << 9) |
                                 (unsigned long long)inv;
        atomicMax(&s_gk[par], key);
      }
      __syncthreads();
      // global winner: one b64 read (step tag guarantees freshness)
      kb = s_gk[par];
      int j_w = 511 - (int)((unsigned)kb & 511u);
      if (tid == 0) s_selj[t] = j_w;
      float4 wbx = s_box[j_w];       // uniform addr -> LDS broadcast read
      float wa = __fmul_rn(__fsub_rn(wbx.z, wbx.x),
                           __fsub_rn(wbx.w, wbx.y)); // == s_ar[j_w] bitwise
      float s1 = __fadd_rn(wa, 1e-9f);
      // decay own slot (verified sequence; inter==0 -> wgt==1 exactly)
      float x1 = fmaxf(wbx.x, qx), y1 = fmaxf(wbx.y, qy);
      float x2 = fminf(wbx.z, qz), y2 = fminf(wbx.w, qw);
      float iw = fmaxf(__fsub_rn(x2, x1), 0.f);
      float ih = fmaxf(__fsub_rn(y2, y1), 0.f);
      float inter = __fmul_rn(iw, ih);
      float den = __fsub_rn(__fadd_rn(pa, s1), inter);
      float iou = __fmul_rn(inter, fast_rcp(den));
      float m2 = __fmul_rn(__fmul_rn(iou, iou), -1.44269504089f);
      float wgt = fast_exp2(m2);
      float ns = __fmul_rn(sr, wgt);
      sr = (tid == j_w) ? -INFINITY : ns;
      // no trailing barrier: s_gk is parity-double-buffered; same-parity
      // reuse is separated by the next step's barrier, and step tags make
      // stale residue always lose the atomicMax.
    }
    // verification: final pick >= TAU (also implies never exhausted)
    float gmax = funmap((unsigned)((kb >> 9) & 0xFFFFFFFFull));
    if (tid == 0) s_fail = (gmax < TAU) ? 1 : 0;
    __syncthreads();
    if (!s_fail) {
      // parallel epilogue: gather winner payloads (all picks valid: gmax>=TAU>0)
      if (tid < P) {
        int wj = s_selj[tid];
        oi[tid] = s_n[wj];
        ov[tid] = 1;
        os[tid] = s_s[wj];
        ob[tid] = s_box[wj];
      }
      return; // pruned result verified
    }
  }

  // ------------- fallback: full-V scan, global scores, EXACT math -------------
  __syncthreads();
  float* sg = sfall + (size_t)blk * N;
  for (int v = tid; v < V; v += NMT) {
    const float* c2 = cpf + (size_t)v * 8 + 4;
    int n = __float_as_int(c2[0]);
    sg[v] = __fmul_rn(c2[1], logits[(size_t)(b * N + n) * C + cls]);
  }
  __syncthreads();

  for (int t = 0; t < P; ++t) {
    float bv = -INFINITY; int bi = INT_MAX;
    for (int v = tid; v < V; v += NMT) {
      float sv = sg[v];
      if (sv > bv) { bv = sv; bi = v; }
    }
    #pragma unroll
    for (int off = 32; off; off >>= 1) {
      float ovv = __shfl_down(bv, off); int oii = __shfl_down(bi, off);
      if (ovv > bv || (ovv == bv && oii < bi)) { bv = ovv; bi = oii; }
    }
    if (lane == 0) { s_red[wid] = bv; s_redi[wid] = bi; }
    __syncthreads();
    float wv = -INFINITY; int wi = INT_MAX;
    #pragma unroll
    for (int k = 0; k < NW; ++k) {
      float v = s_red[k]; int i = s_redi[k];
      if (v > wv || (v == wv && i < wi)) { wv = v; wi = i; }
    }
    __syncthreads(); // partials consumed
    if (wi == INT_MAX) {
      if (tid == 0) for (int u = t; u < P; ++u) {
        oi[u] = 0; ov[u] = 0; os[u] = 0.f;
        ob[u] = make_float4(0.f, 0.f, 0.f, 0.f);
      }
      break; // uniform
    }
    int vd = (wv > 0.0f) ? 1 : 0;
    const float* cw = cpf + (size_t)wi * 8;
    if (tid == 0) {
      int n = __float_as_int(cw[4]);
      oi[t] = n; ov[t] = vd;
      os[t] = __fmul_rn(cw[5], logits[(size_t)(b * N + n) * C + cls]);
      ob[t] = make_float4(cw[0], cw[1], cw[2], cw[3]);
    }
    float w0, w1, w2, w3;
    if (vd) { w0 = cw[0]; w1 = cw[1]; w2 = cw[2]; w3 = cw[3]; }
    else    { w0 = w1 = w2 = w3 = 0.f; }
    float wa = __fmul_rn(__fsub_rn(w2, w0), __fsub_rn(w3, w1));
    for (int v = tid; v < V; v += NMT) {
      float sv = (v == wi) ? -INFINITY : sg[v];
      const float* cq = cpf + (size_t)v * 8;
      float x1 = fmaxf(w0, cq[0]), y1 = fmaxf(w1, cq[1]);
      float x2 = fminf(w2, cq[2]), y2 = fminf(w3, cq[3]);
      float iw = fmaxf(__fsub_rn(x2, x1), 0.f);
      float ih = fmaxf(__fsub_rn(y2, y1), 0.f);
      float inter = __fmul_rn(iw, ih);
      float den = __fadd_rn(__fsub_rn(__fadd_rn(wa, cq[6]), inter), 1e-9f);
      float iou = __fdiv_rn(inter, den);
      float wgt = expf(-__fmul_rn(iou, iou));
      sg[v] = __fmul_rn(sv, wgt);
    }
    __syncthreads();
  }
}

// ---------------------------------------------------------------------------
// Kernel 4: stable top-100 via hierarchical bitonic sort of 2048 packed
// 64-bit keys. Same network and key packing as before (bit-identical
// output), but with an OWNERSHIP layout: thread owns 4 contiguous keys,
// wave owns a contiguous 256-chunk. Substages with j>=256 cross waves ->
// barrier (only 6 of 66); 4<=j<=128 stay inside one wave's chunk ->
// wave-synchronous LDS compare-exchange, NO barrier (same-wave DS ops are
// processed in order, lanes convergent); j<=2 stay inside one thread's 4
// registers -> one read, two swap levels, one write. 10 barriers vs 66.
// key = (fmap(value) << 32) | ~index: descending key order == lax.top_k's
// stable order (value desc, smallest index on ties); keys unique.
// ---------------------------------------------------------------------------
__global__ __launch_bounds__(TKT) void k_topk(
    const float* __restrict__ score, const float* __restrict__ logits,
    const float* __restrict__ obox, const int* __restrict__ oidx,
    const int* __restrict__ oval, const float* __restrict__ osc,
    float* __restrict__ out) {
  __shared__ unsigned long long s_key[TKN];
  __shared__ int s_fi[TKN];

  int b = blockIdx.x;
  int tid = threadIdx.x;
  int lane = tid & 63, wid = tid >> 6;
  size_t base = (size_t)b * NC * P;

  // ownership fill: thread tid owns keys 4*tid .. 4*tid+3
  // (pads sort after everything real: -INF < -BIGF)
  #pragma unroll
  for (int q = 0; q < 4; ++q) {
    int j = 4 * tid + q;
    unsigned hi;
    if (j < NC * P) {
      int vl = oval[base + j];
      float c = vl ? osc[base + j] : -BIGF;
      s_fi[j] = oidx[base + j];
      hi = fmap(c);
    } else {
      s_fi[j] = 0;
      hi = fmap(-INFINITY);
    }
    s_key[j] = ((unsigned long long)hi << 32) | (unsigned)(~j);
  }
  // no barrier needed: k=2..256 phases touch only the owning wave's chunk,
  // and each element was written by its owning thread above.

  for (int k = 2; k <= TKN; k <<= 1) {
    int j = k >> 1;
    // ---- cross-wave substages (j >= 256): barriered ----
    for (; j >= 256; j >>= 1) {
      __syncthreads();
      #pragma unroll
      for (int q = 0; q < TKN / 2 / TKT; ++q) {
        int p = tid + q * TKT;
        int i = ((p & ~(j - 1)) << 1) | (p & (j - 1));
        int l = i | j;
        unsigned long long a = s_key[i], bb = s_key[l];
        bool desc = ((i & k) == 0);
        if (desc ? (a < bb) : (a > bb)) { s_key[i] = bb; s_key[l] = a; }
      }
    }
    if (k >= 512) __syncthreads(); // wave-local reads follow cross-wave writes
    // ---- wave-local substages (4 <= j <= 128): no barrier ----
    for (; j >= 4; j >>= 1) {
      #pragma unroll
      for (int q = 0; q < 2; ++q) {
        int pl = lane + q * 64;                       // local pair 0..127
        int il = ((pl & ~(j - 1)) << 1) | (pl & (j - 1));
        int i = (wid << 8) | il;                      // within own 256-chunk
        int l = i | j;
        unsigned long long a = s_key[i], bb = s_key[l];
        bool desc = ((i & k) == 0);
        if (desc ? (a < bb) : (a > bb)) { s_key[i] = bb; s_key[l] = a; }
      }
    }
    // ---- register substages (j = 2, 1) on own 4 contiguous keys ----
    {
      int e0 = tid << 2;
      unsigned long long v0 = s_key[e0],     v1 = s_key[e0 + 1];
      unsigned long long v2 = s_key[e0 + 2], v3 = s_key[e0 + 3];
      if (k > 2) {
        bool desc = ((e0 & k) == 0); // same for all 4 elements (k >= 4)
        // j=2: (v0,v2), (v1,v3)
        if (desc ? (v0 < v2) : (v0 > v2)) { unsigned long long t = v0; v0 = v2; v2 = t; }
        if (desc ? (v1 < v3) : (v1 > v3)) { unsigned long long t = v1; v1 = v3; v3 = t; }
        // j=1: (v0,v1), (v2,v3)
        if (desc ? (v0 < v1) : (v0 > v1)) { unsigned long long t = v0; v0 = v1; v1 = t; }
        if (desc ? (v2 < v3) : (v2 > v3)) { unsigned long long t = v2; v2 = v3; v3 = t; }
      } else {
        // k == 2, j=1: pair (v0,v1) desc (e0&2==0), pair (v2,v3) asc
        if (v0 < v1) { unsigned long long t = v0; v0 = v1; v1 = t; }
        if (v2 > v3) { unsigned long long t = v2; v2 = v3; v3 = t; }
      }
      s_key[e0] = v0; s_key[e0 + 1] = v1; s_key[e0 + 2] = v2; s_key[e0 + 3] = v3;
    }
  }
  __syncthreads();

  // logit_out: [B][P][C]
  for (int kk = tid; kk < P * C; kk += TKT) {
    int t = kk / C, cls = kk % C;
    unsigned long long kt = s_key[t];
    float sv = funmap((unsigned)(kt >> 32));
    int j = (int)(~(unsigned)kt);
    bool okp = sv > -BIGF * 0.5f;
    float o = 0.f;
    if (okp) {
      int fi = s_fi[j];
      int bn = b * N + fi;
      o = __fmul_rn(score[bn], logits[(size_t)bn * C + cls]);
    }
    out[((size_t)b * P + t) * C + cls] = o;
  }
  // proposal: [B][P][4] from per-pick winner boxes
  for (int kk = tid; kk < P * 4; kk += TKT) {
    int t = kk / 4, d = kk % 4;
    unsigned long long kt = s_key[t];
    float sv = funmap((unsigned)(kt >> 32));
    int j = (int)(~(unsigned)kt);
    bool okp = sv > -BIGF * 0.5f;
    float o = 0.f;
    if (okp) o = obox[(base + j) * 4 + d];
    out[(size_t)B * P * C + ((size_t)b * P + t) * 4 + d] = o;
  }
}

// ---------------------------------------------------------------------------
extern "C" void kernel_launch(void* const* d_in, const int* in_sizes, int n_in,
                              void* d_out, int out_size, void* d_ws, size_t ws_size,
                              hipStream_t stream) {
  const float* score   = (const float*)d_in[0]; // (B,N,1)
  const float* logits  = (const float*)d_in[1]; // (B,N,C)
  const float* regress = (const float*)d_in[2]; // (B,N,4)
  const float* anchors = (const float*)d_in[3]; // (N,4)
  float* out = (float*)d_out;

  char* ws = (char*)d_ws;
  float*    cpack = (float*)(ws + OFF_CPACK);
  unsigned* mask  = (unsigned*)(ws + OFF_MASK);
  int*      bcnt  = (int*)(ws + OFF_BCNT);
  int*      vcnt  = (int*)(ws + OFF_VCNT);
  int*      oidx  = (int*)(ws + OFF_OIDX);
  int*      oval  = (int*)(ws + OFF_OVAL);
  float*    osc   = (float*)(ws + OFF_OSC);
  float*    obox  = (float*)(ws + OFF_OBOX);
  float*    sfall = (float*)(ws + OFF_SFALL);

  k_valid<<<dim3(NB, B), 256, 0, stream>>>(score, logits, mask, bcnt);
  k_compact<<<dim3(GB, B), 256, 0, stream>>>(score, regress, anchors, mask,
                                             bcnt, cpack, vcnt);
  k_nms<<<B * NC, NMT, 0, stream>>>(logits, cpack, vcnt, sfall, oidx, oval,
                                    osc, obox);
  k_topk<<<B, TKT, 0, stream>>>(score, logits, obox, oidx, oval, osc, out);
}

// Round 10
// 79.165 us; speedup vs baseline: 1.1125x; 1.1125x over previous
//
#include <hip/hip_runtime.h>
#include <climits>
#include <cstdint>

namespace {
constexpr int B = 4, N = 20000, C = 21, P = 100, NC = 20; // NC = C-1
constexpr float THR  = 0.7f;
constexpr float BIGF = 1.0e9f;
constexpr float MAXR = 4.135166556742356f; // |log(16/1000)| rounded to f32
constexpr float TAU  = 0.8f;               // prune threshold (verified post-hoc)
constexpr int NMT  = 512;                  // k_nms block size
constexpr int PCAP = NMT;                  // pruned-list capacity = 1 slot/thread
constexpr int TKN  = 2048;                 // padded topk candidate count
constexpr int TKT  = 512;                  // k_topk block size (8 waves)
constexpr int NB   = (N + 255) / 256;      // 79 k_valid blocks per image
constexpr int GPB  = 2;                    // k_valid blocks per compact block
constexpr int GB   = (NB + GPB - 1) / GPB; // 40 compact blocks per image

// ws layout (bytes)
constexpr size_t OFF_CPACK = 0;                                  // B*N*8 f32 packed cand
constexpr size_t OFF_MASK  = OFF_CPACK + (size_t)B * N * 32;     // B*N u32
constexpr size_t OFF_BCNT  = OFF_MASK  + (size_t)B * N * 4;      // B*NB i32 (+pad)
constexpr size_t OFF_VCNT  = OFF_BCNT  + 2048;                   // B i32 (+pad)
constexpr size_t OFF_OIDX  = OFF_VCNT  + 64;                     // B*NC*P i32
constexpr size_t OFF_OVAL  = OFF_OIDX  + (size_t)B * NC * P * 4; // B*NC*P i32
constexpr size_t OFF_OSC   = OFF_OVAL  + (size_t)B * NC * P * 4; // B*NC*P f32 (orig le)
constexpr size_t OFF_OBOX  = OFF_OSC   + (size_t)B * NC * P * 4; // B*NC*P f32x4
constexpr size_t OFF_SFALL = OFF_OBOX  + (size_t)B * NC * P * 16;// B*NC*N f32 fallback
} // namespace

// ---------------------------------------------------------------------------
// DPP wave64 fmax reduce (VALU-only); result broadcast via readlane 63.
// ---------------------------------------------------------------------------
template <int CTRL, int RM>
__device__ __forceinline__ float dpp_fmax(float x) {
  int t = __builtin_amdgcn_update_dpp(__float_as_int(x), __float_as_int(x),
                                      CTRL, RM, 0xF, false);
  return fmaxf(x, __int_as_float(t));
}
__device__ __forceinline__ float wave_fmax64(float x) {
  x = dpp_fmax<0x111, 0xF>(x); // row_shr:1
  x = dpp_fmax<0x112, 0xF>(x); // row_shr:2
  x = dpp_fmax<0x114, 0xF>(x); // row_shr:4
  x = dpp_fmax<0x118, 0xF>(x); // row_shr:8
  x = dpp_fmax<0x142, 0xA>(x); // row_bcast:15 -> rows 1,3
  x = dpp_fmax<0x143, 0xC>(x); // row_bcast:31 -> rows 2,3
  return __int_as_float(__builtin_amdgcn_readlane(__float_as_int(x), 63));
}
// fast native ops for the decay weights (selection-only values; exp2(-0)=1
// exactly so non-overlapping candidates stay bit-identical to np)
__device__ __forceinline__ float fast_rcp(float x) {
  return __builtin_amdgcn_rcpf(x);
}
__device__ __forceinline__ float fast_exp2(float x) {
  return __builtin_amdgcn_exp2f(x);
}
// monotonic float<->uint order map (no NaNs present)
__device__ __forceinline__ unsigned fmap(float v) {
  unsigned u = __float_as_uint(v);
  return (u & 0x80000000u) ? ~u : (u | 0x80000000u);
}
__device__ __forceinline__ float funmap(unsigned u) {
  return __uint_as_float((u & 0x80000000u) ? (u ^ 0x80000000u) : ~u);
}

// ---------------------------------------------------------------------------
// Kernel 1: per-anchor le/argmax/valid + tau bitmask + per-block valid count.
// ---------------------------------------------------------------------------
__global__ __launch_bounds__(256) void k_valid(
    const float* __restrict__ score, const float* __restrict__ logits,
    unsigned* __restrict__ mask, int* __restrict__ bcnt) {
  __shared__ int ws[4];
  int tid = threadIdx.x;
  int n = blockIdx.x * 256 + tid;
  int b = blockIdx.y;
  unsigned mk = 0;
  if (n < N) {
    int bn = b * N + n;
    float sc = score[bn];
    const float* lg = logits + (size_t)bn * C;
    float le[C];
    float ms = -INFINITY;
    int lab = 0;
    #pragma unroll
    for (int c = 0; c < C; ++c) {
      le[c] = __fmul_rn(sc, lg[c]);
      if (le[c] > ms) { ms = le[c]; lab = c; }  // strict > keeps first max
    }
    if (ms >= THR && lab > 0) {
      mk = 1u << 20;
      #pragma unroll
      for (int c = 1; c < C; ++c)
        if (le[c] >= TAU) mk |= 1u << (c - 1);
    }
    mask[bn] = mk;
  }
  unsigned long long vb = __ballot(mk != 0);
  if ((tid & 63) == 0) ws[tid >> 6] = __popcll(vb);
  __syncthreads();
  if (tid == 0) bcnt[b * NB + blockIdx.x] = ws[0] + ws[1] + ws[2] + ws[3];
}

// ---------------------------------------------------------------------------
// Kernel 2: segmented stable compaction + box decode into packed 32B records
// {x1,y1,x2,y2, n(bits), score, area, mask(bits)}. Grid (GB, B), 256 thr.
// ---------------------------------------------------------------------------
__global__ __launch_bounds__(256) void k_compact(
    const float* __restrict__ score, const float* __restrict__ regress,
    const float* __restrict__ anchors, const unsigned* __restrict__ mask,
    const int* __restrict__ bcnt, float* __restrict__ cpack,
    int* __restrict__ vcnt) {
  __shared__ int s_base[4], s_tot[4], s_scan[4];
  int g = blockIdx.x, b = blockIdx.y;
  int tid = threadIdx.x, lane = tid & 63, wid = tid >> 6;
  int idx0 = g * GPB;
  int bv = (tid < idx0) ? bcnt[b * NB + tid] : 0;
  int tv = (tid < NB) ? bcnt[b * NB + tid] : 0;
  #pragma unroll
  for (int off = 32; off; off >>= 1) {
    bv += __shfl_down(bv, off);
    tv += __shfl_down(tv, off);
  }
  if (lane == 0) { s_base[wid] = bv; s_tot[wid] = tv; }
  __syncthreads();
  int base = s_base[0] + s_base[1] + s_base[2] + s_base[3];
  if (g == 0 && tid == 0) vcnt[b] = s_tot[0] + s_tot[1] + s_tot[2] + s_tot[3];

  int n0 = g * (GPB * 256) + tid * GPB;
  unsigned bits = 0; int cnt = 0;
  #pragma unroll
  for (int j = 0; j < GPB; ++j) {
    int n = n0 + j;
    if (n < N && (mask[b * N + n] & (1u << 20))) { bits |= 1u << j; cnt++; }
  }
  int inc = cnt;
  #pragma unroll
  for (int off = 1; off < 64; off <<= 1) {
    int o = __shfl_up(inc, off);
    if (lane >= off) inc += o;
  }
  if (lane == 63) s_scan[wid] = inc;
  __syncthreads();
  int woff = 0;
  for (int k = 0; k < wid; ++k) woff += s_scan[k];
  int pos = base + woff + inc - cnt;
  #pragma unroll
  for (int j = 0; j < GPB; ++j) {
    if (!((bits >> j) & 1u)) continue;
    int n = n0 + j;
    int bn = b * N + n;
    const float* an = anchors + (size_t)n * 4;
    float ax1 = an[0], ay1 = an[1], ax2 = an[2], ay2 = an[3];
    float aw = __fsub_rn(ax2, ax1), ah = __fsub_rn(ay2, ay1);
    float acx = __fadd_rn(ax1, __fmul_rn(0.5f, aw));
    float acy = __fadd_rn(ay1, __fmul_rn(0.5f, ah));
    const float* rg = regress + (size_t)bn * 4;
    float dx = rg[0], dy = rg[1];
    float dw = fminf(fmaxf(rg[2], -MAXR), MAXR);
    float dh = fminf(fmaxf(rg[3], -MAXR), MAXR);
    float cx = __fadd_rn(acx, __fmul_rn(dx, aw));
    float cy = __fadd_rn(acy, __fmul_rn(dy, ah));
    float w = __fmul_rn(aw, expf(dw));
    float h = __fmul_rn(ah, expf(dh));
    float hw = __fmul_rn(0.5f, w), hh = __fmul_rn(0.5f, h);
    float x1 = fminf(fmaxf(__fsub_rn(cx, hw), 0.f), 1.f);
    float y1 = fminf(fmaxf(__fsub_rn(cy, hh), 0.f), 1.f);
    float x2 = fminf(fmaxf(__fadd_rn(cx, hw), 0.f), 1.f);
    float y2 = fminf(fmaxf(__fadd_rn(cy, hh), 0.f), 1.f);
    float area = __fmul_rn(__fsub_rn(x2, x1), __fsub_rn(y2, y1));
    unsigned mk = mask[bn];
    float4* cp = reinterpret_cast<float4*>(cpack) + ((size_t)b * N + pos) * 2;
    cp[0] = make_float4(x1, y1, x2, y2);
    cp[1] = make_float4(__int_as_float(n), score[bn], area, __uint_as_float(mk));
    pos++;
  }
}

// ---------------------------------------------------------------------------
// Kernel 3: soft-NMS. One block per (image,class), 512 threads, 1 slot/thread
// (the measured-best structure; at its latency floor ~570 ns/step). Per step:
// decay own slot -> wave argmax (DPP fmax + ballot) -> lane0 publishes ONE
// step-tagged packed key via LDS atomicMax into a parity-double-buffered u64:
//   key = ((t+1)<<41) | (fmap(val)<<9) | (511-tid)
// Monotone step tag makes stale same-parity residue always lose -> no reset,
// one barrier/step. Post-barrier: one ds_read_b64 gives the global winner,
// then the winner box via uniform LDS broadcast. Decay math is the exact
// verified sequence (fast rcp/exp2; inter==0 -> wgt==1 exactly). Exhaustion
// keeps the final key value < TAU -> exact full-V fallback. s_box zero-init
// keeps empty slots NaN-free.
// ---------------------------------------------------------------------------
__global__ __launch_bounds__(NMT) void k_nms(
    const float* __restrict__ logits, const float* __restrict__ cpack,
    const int* __restrict__ vcnt, float* __restrict__ sfall,
    int* __restrict__ oidx, int* __restrict__ oval,
    float* __restrict__ osc, float* __restrict__ obox) {
  constexpr int NW = NMT / 64;
  __shared__ float4 s_box[PCAP];
  __shared__ float  s_ar[PCAP], s_s[PCAP];
  __shared__ int    s_n[PCAP];
  __shared__ int    s_selj[P];
  __shared__ int    s_wcnt[NW];
  __shared__ int    s_fail;
  __shared__ unsigned long long s_gk[2]; // parity-double-buffered global key
  __shared__ float  s_red[NW];
  __shared__ int    s_redi[NW];

  int blk = blockIdx.x;  // 0..B*NC-1
  int b = blk / NC;
  int cls = blk % NC + 1;
  int V = vcnt[b];
  int tid = threadIdx.x;
  int lane = tid & 63, wid = tid >> 6;
  const float* cpf = cpack + (size_t)b * N * 8;
  int* oi = oidx + (size_t)blk * P;
  int* ov = oval + (size_t)blk * P;
  float* os = osc + (size_t)blk * P;
  float4* ob = reinterpret_cast<float4*>(obox) + (size_t)blk * P;
  unsigned clsbit = 1u << (cls - 1);

  // zero-init s_box so empty slots read a harmless zero box
  s_box[tid] = make_float4(0.f, 0.f, 0.f, 0.f);
  if (tid == 0) { s_gk[0] = 0ull; s_gk[1] = 0ull; }

  // ---- pass 1: count candidates with le >= TAU for this class ----
  int ch = (V + NMT - 1) / NMT;
  int v0 = tid * ch, v1 = min(v0 + ch, V);
  int cnt = 0;
  for (int v = v0; v < v1; ++v) {
    unsigned mk = __float_as_uint(cpf[(size_t)v * 8 + 7]);
    if (mk & clsbit) cnt++;
  }
  int inc = cnt;
  #pragma unroll
  for (int off = 1; off < 64; off <<= 1) {
    int o = __shfl_up(inc, off);
    if (lane >= off) inc += o;
  }
  if (lane == 63) s_wcnt[wid] = inc;
  __syncthreads();
  int woff = 0;
  for (int k = 0; k < wid; ++k) woff += s_wcnt[k];
  int pcnt = 0;
  #pragma unroll
  for (int k = 0; k < NW; ++k) pcnt += s_wcnt[k];
  int pos = woff + inc - cnt;
  // ---- pass 2: fill LDS for passing candidates (stable order) ----
  for (int v = v0; v < v1; ++v) {
    const float4* cp = reinterpret_cast<const float4*>(cpf) + (size_t)v * 2;
    float4 f2 = cp[1];
    unsigned mk = __float_as_uint(f2.w);
    if (mk & clsbit) {
      if (pos < PCAP) {
        float4 f1 = cp[0];
        int n = __float_as_int(f2.x);
        float lg = logits[(size_t)(b * N + n) * C + cls];
        s_s[pos]   = __fmul_rn(f2.y, lg);
        s_box[pos] = f1;
        s_ar[pos]  = f2.z;
        s_n[pos]   = n;
      }
      pos++;
    }
  }
  __syncthreads();

  bool fail0 = (pcnt > PCAP);
  if (!fail0) {
    // ---- per-thread single-slot state ----
    bool in = tid < pcnt;
    float4 q = s_box[tid];
    float sr = in ? s_s[tid] : -INFINITY;
    float qx = q.x, qy = q.y, qz = q.z, qw = q.w;
    float pa = in ? s_ar[tid] : 0.f;
    unsigned long long kb = 0ull;

    for (int t = 0; t < P; ++t) {
      int par = t & 1;
      // wave argmax of sr (ties -> smallest lane = smallest slot)
      float lm = wave_fmax64(sr);
      unsigned long long bm = __ballot(sr == lm);
      int lane_w = __ffsll(bm) - 1;
      if (lane == 0) {
        unsigned inv = 511u - (unsigned)(wid * 64 + lane_w);
        unsigned long long key = ((unsigned long long)(t + 1) << 41) |
                                 ((unsigned long long)fmap(lm) << 9) |
                                 (unsigned long long)inv;
        atomicMax(&s_gk[par], key);
      }
      __syncthreads();
      // global winner: one b64 read (step tag guarantees freshness)
      kb = s_gk[par];
      int j_w = 511 - (int)((unsigned)kb & 511u);
      if (tid == 0) s_selj[t] = j_w;
      float4 wbx = s_box[j_w];       // uniform addr -> LDS broadcast read
      float wa = __fmul_rn(__fsub_rn(wbx.z, wbx.x),
                           __fsub_rn(wbx.w, wbx.y)); // == s_ar[j_w] bitwise
      float s1 = __fadd_rn(wa, 1e-9f);
      // decay own slot (verified sequence; inter==0 -> wgt==1 exactly)
      float x1 = fmaxf(wbx.x, qx), y1 = fmaxf(wbx.y, qy);
      float x2 = fminf(wbx.z, qz), y2 = fminf(wbx.w, qw);
      float iw = fmaxf(__fsub_rn(x2, x1), 0.f);
      float ih = fmaxf(__fsub_rn(y2, y1), 0.f);
      float inter = __fmul_rn(iw, ih);
      float den = __fsub_rn(__fadd_rn(pa, s1), inter);
      float iou = __fmul_rn(inter, fast_rcp(den));
      float m2 = __fmul_rn(__fmul_rn(iou, iou), -1.44269504089f);
      float wgt = fast_exp2(m2);
      float ns = __fmul_rn(sr, wgt);
      sr = (tid == j_w) ? -INFINITY : ns;
      // no trailing barrier: s_gk is parity-double-buffered; same-parity
      // reuse is separated by the next step's barrier, and step tags make
      // stale residue always lose the atomicMax.
    }
    // verification: final pick >= TAU (also implies never exhausted)
    float gmax = funmap((unsigned)((kb >> 9) & 0xFFFFFFFFull));
    if (tid == 0) s_fail = (gmax < TAU) ? 1 : 0;
    __syncthreads();
    if (!s_fail) {
      // parallel epilogue: gather winner payloads (all picks valid: gmax>=TAU>0)
      if (tid < P) {
        int wj = s_selj[tid];
        oi[tid] = s_n[wj];
        ov[tid] = 1;
        os[tid] = s_s[wj];
        ob[tid] = s_box[wj];
      }
      return; // pruned result verified
    }
  }

  // ------------- fallback: full-V scan, global scores, EXACT math -------------
  __syncthreads();
  float* sg = sfall + (size_t)blk * N;
  for (int v = tid; v < V; v += NMT) {
    const float* c2 = cpf + (size_t)v * 8 + 4;
    int n = __float_as_int(c2[0]);
    sg[v] = __fmul_rn(c2[1], logits[(size_t)(b * N + n) * C + cls]);
  }
  __syncthreads();

  for (int t = 0; t < P; ++t) {
    float bv = -INFINITY; int bi = INT_MAX;
    for (int v = tid; v < V; v += NMT) {
      float sv = sg[v];
      if (sv > bv) { bv = sv; bi = v; }
    }
    #pragma unroll
    for (int off = 32; off; off >>= 1) {
      float ovv = __shfl_down(bv, off); int oii = __shfl_down(bi, off);
      if (ovv > bv || (ovv == bv && oii < bi)) { bv = ovv; bi = oii; }
    }
    if (lane == 0) { s_red[wid] = bv; s_redi[wid] = bi; }
    __syncthreads();
    float wv = -INFINITY; int wi = INT_MAX;
    #pragma unroll
    for (int k = 0; k < NW; ++k) {
      float v = s_red[k]; int i = s_redi[k];
      if (v > wv || (v == wv && i < wi)) { wv = v; wi = i; }
    }
    __syncthreads(); // partials consumed
    if (wi == INT_MAX) {
      if (tid == 0) for (int u = t; u < P; ++u) {
        oi[u] = 0; ov[u] = 0; os[u] = 0.f;
        ob[u] = make_float4(0.f, 0.f, 0.f, 0.f);
      }
      break; // uniform
    }
    int vd = (wv > 0.0f) ? 1 : 0;
    const float* cw = cpf + (size_t)wi * 8;
    if (tid == 0) {
      int n = __float_as_int(cw[4]);
      oi[t] = n; ov[t] = vd;
      os[t] = __fmul_rn(cw[5], logits[(size_t)(b * N + n) * C + cls]);
      ob[t] = make_float4(cw[0], cw[1], cw[2], cw[3]);
    }
    float w0, w1, w2, w3;
    if (vd) { w0 = cw[0]; w1 = cw[1]; w2 = cw[2]; w3 = cw[3]; }
    else    { w0 = w1 = w2 = w3 = 0.f; }
    float wa = __fmul_rn(__fsub_rn(w2, w0), __fsub_rn(w3, w1));
    for (int v = tid; v < V; v += NMT) {
      float sv = (v == wi) ? -INFINITY : sg[v];
      const float* cq = cpf + (size_t)v * 8;
      float x1 = fmaxf(w0, cq[0]), y1 = fmaxf(w1, cq[1]);
      float x2 = fminf(w2, cq[2]), y2 = fminf(w3, cq[3]);
      float iw = fmaxf(__fsub_rn(x2, x1), 0.f);
      float ih = fmaxf(__fsub_rn(y2, y1), 0.f);
      float inter = __fmul_rn(iw, ih);
      float den = __fadd_rn(__fsub_rn(__fadd_rn(wa, cq[6]), inter), 1e-9f);
      float iou = __fdiv_rn(inter, den);
      float wgt = expf(-__fmul_rn(iou, iou));
      sg[v] = __fmul_rn(sv, wgt);
    }
    __syncthreads();
  }
}

// ---------------------------------------------------------------------------
// Kernel 4: stable top-100 via REGISTER bitonic sort of 2048 packed 64-bit
// keys: 4 keys/thread (element i = 4*tid+q). Same network & key packing as
// before -> bit-identical output. Substage distance j: j<=2 = in-thread
// register swaps; 4<=j<=128 = __shfl_xor compare-exchange (partner thread
// tid^(j>>2), same slot q; no LDS, no barrier); j>=256 (6 of 66 substages)
// = parity-double-buffered LDS exchange with ONE barrier each. Direction
// bits reduce to tid&(k>>2) / tid&(j>>2) (uniform per thread, SALU).
// key = (fmap(value) << 32) | ~index: descending key order == lax.top_k's
// stable order (value desc, smallest index on ties); keys unique.
// Fill vectorized: threads 0..499 own 4 real entries (int4/float4 loads,
// 16B-aligned), threads 500..511 pure pads (-INF sorts after -BIGF).
// ---------------------------------------------------------------------------
__global__ __launch_bounds__(TKT) void k_topk(
    const float* __restrict__ score, const float* __restrict__ logits,
    const float* __restrict__ obox, const int* __restrict__ oidx,
    const int* __restrict__ oval, const float* __restrict__ osc,
    float* __restrict__ out) {
  __shared__ unsigned long long s_k2[2][TKN];
  __shared__ int s_fi[TKN];

  int b = blockIdx.x;
  int tid = threadIdx.x;
  size_t base = (size_t)b * NC * P;

  unsigned long long v0, v1, v2, v3;
  {
    int j0 = 4 * tid;
    if (j0 + 3 < NC * P) { // threads 0..499: fully real (2000 = 4*500)
      int4   vl4 = *reinterpret_cast<const int4*>(oval + base + j0);
      float4 sc4 = *reinterpret_cast<const float4*>(osc + base + j0);
      int4   fi4 = *reinterpret_cast<const int4*>(oidx + base + j0);
      s_fi[j0]     = fi4.x; s_fi[j0 + 1] = fi4.y;
      s_fi[j0 + 2] = fi4.z; s_fi[j0 + 3] = fi4.w;
      v0 = ((unsigned long long)fmap(vl4.x ? sc4.x : -BIGF) << 32) |
           (unsigned)(~(j0 + 0));
      v1 = ((unsigned long long)fmap(vl4.y ? sc4.y : -BIGF) << 32) |
           (unsigned)(~(j0 + 1));
      v2 = ((unsigned long long)fmap(vl4.z ? sc4.z : -BIGF) << 32) |
           (unsigned)(~(j0 + 2));
      v3 = ((unsigned long long)fmap(vl4.w ? sc4.w : -BIGF) << 32) |
           (unsigned)(~(j0 + 3));
    } else {               // threads 500..511: pure pads
      s_fi[j0] = 0; s_fi[j0 + 1] = 0; s_fi[j0 + 2] = 0; s_fi[j0 + 3] = 0;
      unsigned long long hi = (unsigned long long)fmap(-INFINITY) << 32;
      v0 = hi | (unsigned)(~(j0 + 0));
      v1 = hi | (unsigned)(~(j0 + 1));
      v2 = hi | (unsigned)(~(j0 + 2));
      v3 = hi | (unsigned)(~(j0 + 3));
    }
  }

  // keep-max/min select (keys unique; no equality case)
  auto cmpx = [](unsigned long long& a, unsigned long long pv, bool keepmax) {
    bool agt = a > pv;
    a = (keepmax == agt) ? a : pv;
  };
  // shfl compare-exchange substage, 4 <= j <= 128
  auto shfl_stage = [&](int k, int j) {
    int xd = j >> 2;
    bool up = ((tid & xd) == 0);
    bool desc = ((tid & (k >> 2)) == 0);
    bool keepmax = (up == desc);
    unsigned long long p0 = __shfl_xor(v0, xd);
    unsigned long long p1 = __shfl_xor(v1, xd);
    unsigned long long p2 = __shfl_xor(v2, xd);
    unsigned long long p3 = __shfl_xor(v3, xd);
    cmpx(v0, p0, keepmax); cmpx(v1, p1, keepmax);
    cmpx(v2, p2, keepmax); cmpx(v3, p3, keepmax);
  };
  // in-thread register substages (j = 2, 1) for k >= 4
  auto reg_stage = [&](int k) {
    bool desc = ((tid & (k >> 2)) == 0);
    auto sw = [&](unsigned long long& a, unsigned long long& bb) {
      if (desc ? (a < bb) : (a > bb)) { unsigned long long t = a; a = bb; bb = t; }
    };
    sw(v0, v2); sw(v1, v3); // j = 2
    sw(v0, v1); sw(v2, v3); // j = 1
  };
  // cross-wave LDS substage, j >= 256; one barrier, parity-buffered
  auto lds_stage = [&](int k, int j, int par) {
    unsigned long long* buf = s_k2[par];
    int j0 = 4 * tid;
    buf[j0] = v0; buf[j0 + 1] = v1; buf[j0 + 2] = v2; buf[j0 + 3] = v3;
    __syncthreads();
    int pj = 4 * (tid ^ (j >> 2));
    unsigned long long p0 = buf[pj], p1 = buf[pj + 1];
    unsigned long long p2 = buf[pj + 2], p3 = buf[pj + 3];
    bool up = ((tid & (j >> 2)) == 0);
    bool desc = ((tid & (k >> 2)) == 0);
    bool keepmax = (up == desc);
    cmpx(v0, p0, keepmax); cmpx(v1, p1, keepmax);
    cmpx(v2, p2, keepmax); cmpx(v3, p3, keepmax);
  };

  // k = 2: (v0,v1) descending, (v2,v3) ascending
  { if (v0 < v1) { unsigned long long t = v0; v0 = v1; v1 = t; }
    if (v2 > v3) { unsigned long long t = v2; v2 = v3; v3 = t; } }
  reg_stage(4);
  #pragma unroll
  for (int k = 8; k <= 256; k <<= 1) {
    #pragma unroll
    for (int j = k >> 1; j >= 4; j >>= 1) shfl_stage(k, j);
    reg_stage(k);
  }
  // k = 512
  lds_stage(512, 256, 0);
  #pragma unroll
  for (int j = 128; j >= 4; j >>= 1) shfl_stage(512, j);
  reg_stage(512);
  // k = 1024
  lds_stage(1024, 512, 1);
  lds_stage(1024, 256, 0);
  #pragma unroll
  for (int j = 128; j >= 4; j >>= 1) shfl_stage(1024, j);
  reg_stage(1024);
  // k = 2048
  lds_stage(2048, 1024, 1);
  lds_stage(2048, 512, 0);
  lds_stage(2048, 256, 1);
  #pragma unroll
  for (int j = 128; j >= 4; j >>= 1) shfl_stage(2048, j);
  reg_stage(2048);

  // publish sorted keys (buffer 0 free: its last reads completed before the
  // k=2048/j=256 stage's barrier)
  {
    int j0 = 4 * tid;
    unsigned long long* buf = s_k2[0];
    buf[j0] = v0; buf[j0 + 1] = v1; buf[j0 + 2] = v2; buf[j0 + 3] = v3;
  }
  __syncthreads();
  const unsigned long long* s_key = s_k2[0];

  // logit_out: [B][P][C]
  for (int kk = tid; kk < P * C; kk += TKT) {
    int t = kk / C, cls = kk % C;
    unsigned long long kt = s_key[t];
    float sv = funmap((unsigned)(kt >> 32));
    int j = (int)(~(unsigned)kt);
    bool okp = sv > -BIGF * 0.5f;
    float o = 0.f;
    if (okp) {
      int fi = s_fi[j];
      int bn = b * N + fi;
      o = __fmul_rn(score[bn], logits[(size_t)bn * C + cls]);
    }
    out[((size_t)b * P + t) * C + cls] = o;
  }
  // proposal: [B][P][4] from per-pick winner boxes
  for (int kk = tid; kk < P * 4; kk += TKT) {
    int t = kk / 4, d = kk % 4;
    unsigned long long kt = s_key[t];
    float sv = funmap((unsigned)(kt >> 32));
    int j = (int)(~(unsigned)kt);
    bool okp = sv > -BIGF * 0.5f;
    float o = 0.f;
    if (okp) o = obox[(base + j) * 4 + d];
    out[(size_t)B * P * C + ((size_t)b * P + t) * 4 + d] = o;
  }
}

// ---------------------------------------------------------------------------
extern "C" void kernel_launch(void* const* d_in, const int* in_sizes, int n_in,
                              void* d_out, int out_size, void* d_ws, size_t ws_size,
                              hipStream_t stream) {
  const float* score   = (const float*)d_in[0]; // (B,N,1)
  const float* logits  = (const float*)d_in[1]; // (B,N,C)
  const float* regress = (const float*)d_in[2]; // (B,N,4)
  const float* anchors = (const float*)d_in[3]; // (N,4)
  float* out = (float*)d_out;

  char* ws = (char*)d_ws;
  float*    cpack = (float*)(ws + OFF_CPACK);
  unsigned* mask  = (unsigned*)(ws + OFF_MASK);
  int*      bcnt  = (int*)(ws + OFF_BCNT);
  int*      vcnt  = (int*)(ws + OFF_VCNT);
  int*      oidx  = (int*)(ws + OFF_OIDX);
  int*      oval  = (int*)(ws + OFF_OVAL);
  float*    osc   = (float*)(ws + OFF_OSC);
  float*    obox  = (float*)(ws + OFF_OBOX);
  float*    sfall = (float*)(ws + OFF_SFALL);

  k_valid<<<dim3(NB, B), 256, 0, stream>>>(score, logits, mask, bcnt);
  k_compact<<<dim3(GB, B), 256, 0, stream>>>(score, regress, anchors, mask,
                                             bcnt, cpack, vcnt);
  k_nms<<<B * NC, NMT, 0, stream>>>(logits, cpack, vcnt, sfall, oidx, oval,
                                    osc, obox);
  k_topk<<<B, TKT, 0, stream>>>(score, logits, obox, oidx, oval, osc, out);
}